// Round 5
// baseline (2044.630 us; speedup 1.0000x reference)
//
#include <hip/hip_runtime.h>
#include <hip/hip_bf16.h>
#include <cstddef>

// Problem constants (match reference)
constexpr int B_SZ  = 2;
constexpr int LSEQ  = 2048;
constexpr int DIM   = 768;
constexpr int H_DIM = 1536;
constexpr int DST   = 16;      // D_STATE
constexpr int KW    = 4;       // conv kernel width
constexpr int MROWS = B_SZ * LSEQ;        // 4096
constexpr int HS    = H_DIM * DST;        // 24576

// chunked scan config
constexpr int CCH  = 16;                  // chunks
constexpr int CLEN = LSEQ / CCH;          // 128

// ===========================================================================
// fp32 GEMM: 128x128 tile, 128 threads (2 waves), 16x8 acc/thread.
// Rationale: per kk, 6 ds_read_b128 feed 128 FMAs -> DS-pipe demand ~matches
// VALU (the old 8x8 variant was 1.5x DS-issue-bound; a 4x4 variant is 3x).
// C[M,N] = epi((A [*A2]) @ Bw + bias);  EPI: 0=none, 1=silu, 2=softplus(extra+v)
// Requires M%128==0, N%128==0, K%16==0, 16B-aligned rows.
// ===========================================================================
#define TBM 128
#define TBN 128
#define TBK 16

template <int EPI, bool AMUL>
__global__ __launch_bounds__(128, 2) void gemm_big(
    const float* __restrict__ A, const float* __restrict__ A2,
    const float* __restrict__ Bw, const float* __restrict__ bias,
    const float* __restrict__ extra, float* __restrict__ C,
    int M, int N, int Kd)
{
    __shared__ float As[TBK][TBM];   // [k][m] transposed A tile
    __shared__ float Bs[TBK][TBN];   // [k][n]

    const int tid = threadIdx.x;     // 0..127
    const int n0 = blockIdx.x * TBN;
    const int m0 = blockIdx.y * TBM;
    const int tx = tid & 15;         // 16 col-groups: cols tx*4..+3 and +64
    const int ty = tid >> 4;         // 8 row-groups: rows ty*16..+15

    // B loader: thread covers k-row (tid>>3), 16 cols at ((tid&7)*16)
    const int lb_k = tid >> 3;
    const int lb_n = (tid & 7) * 16;

    float acc[16][8] = {};

    for (int k0 = 0; k0 < Kd; k0 += TBK) {
        // ---- stage A (transposed): each thread owns global row m0+tid,
        //      k-range k0..k0+15 (64B contiguous -> dense coalescing)
        {
            const float* ap = &A[(size_t)(m0 + tid) * Kd + k0];
            float4 a0 = *reinterpret_cast<const float4*>(ap + 0);
            float4 a1 = *reinterpret_cast<const float4*>(ap + 4);
            float4 a2 = *reinterpret_cast<const float4*>(ap + 8);
            float4 a3 = *reinterpret_cast<const float4*>(ap + 12);
            if (AMUL) {
                const float* gp = &A2[(size_t)(m0 + tid) * Kd + k0];
                float4 g0 = *reinterpret_cast<const float4*>(gp + 0);
                float4 g1 = *reinterpret_cast<const float4*>(gp + 4);
                float4 g2 = *reinterpret_cast<const float4*>(gp + 8);
                float4 g3 = *reinterpret_cast<const float4*>(gp + 12);
                a0.x *= g0.x; a0.y *= g0.y; a0.z *= g0.z; a0.w *= g0.w;
                a1.x *= g1.x; a1.y *= g1.y; a1.z *= g1.z; a1.w *= g1.w;
                a2.x *= g2.x; a2.y *= g2.y; a2.z *= g2.z; a2.w *= g2.w;
                a3.x *= g3.x; a3.y *= g3.y; a3.z *= g3.z; a3.w *= g3.w;
            }
            As[ 0][tid] = a0.x; As[ 1][tid] = a0.y; As[ 2][tid] = a0.z; As[ 3][tid] = a0.w;
            As[ 4][tid] = a1.x; As[ 5][tid] = a1.y; As[ 6][tid] = a1.z; As[ 7][tid] = a1.w;
            As[ 8][tid] = a2.x; As[ 9][tid] = a2.y; As[10][tid] = a2.z; As[11][tid] = a2.w;
            As[12][tid] = a3.x; As[13][tid] = a3.y; As[14][tid] = a3.z; As[15][tid] = a3.w;
        }
        // ---- stage B: thread covers one k-row, 16 contiguous cols
        {
            const float* bp = &Bw[(size_t)(k0 + lb_k) * N + n0 + lb_n];
            float4 b0 = *reinterpret_cast<const float4*>(bp + 0);
            float4 b1 = *reinterpret_cast<const float4*>(bp + 4);
            float4 b2 = *reinterpret_cast<const float4*>(bp + 8);
            float4 b3 = *reinterpret_cast<const float4*>(bp + 12);
            *reinterpret_cast<float4*>(&Bs[lb_k][lb_n +  0]) = b0;
            *reinterpret_cast<float4*>(&Bs[lb_k][lb_n +  4]) = b1;
            *reinterpret_cast<float4*>(&Bs[lb_k][lb_n +  8]) = b2;
            *reinterpret_cast<float4*>(&Bs[lb_k][lb_n + 12]) = b3;
        }
        __syncthreads();
#pragma unroll
        for (int kk = 0; kk < TBK; ++kk) {
            // A rows ty*16..+15: 4 broadcast b128 reads. B cols: 2 b128 reads.
            float4 x0 = *reinterpret_cast<const float4*>(&As[kk][ty * 16 + 0]);
            float4 x1 = *reinterpret_cast<const float4*>(&As[kk][ty * 16 + 4]);
            float4 x2 = *reinterpret_cast<const float4*>(&As[kk][ty * 16 + 8]);
            float4 x3 = *reinterpret_cast<const float4*>(&As[kk][ty * 16 + 12]);
            float4 y0 = *reinterpret_cast<const float4*>(&Bs[kk][tx * 4]);
            float4 y1 = *reinterpret_cast<const float4*>(&Bs[kk][tx * 4 + 64]);
            float av[16] = {x0.x, x0.y, x0.z, x0.w, x1.x, x1.y, x1.z, x1.w,
                            x2.x, x2.y, x2.z, x2.w, x3.x, x3.y, x3.z, x3.w};
            float bv[8]  = {y0.x, y0.y, y0.z, y0.w, y1.x, y1.y, y1.z, y1.w};
#pragma unroll
            for (int i = 0; i < 16; ++i)
#pragma unroll
                for (int j = 0; j < 8; ++j)
                    acc[i][j] = fmaf(av[i], bv[j], acc[i][j]);
        }
        __syncthreads();
    }

    // epilogue: cols n0+tx*4+{0..3} and +64; rows m0+ty*16+{0..15}
    const int nc0 = n0 + tx * 4;
    const int nc1 = nc0 + 64;
    float4 bi0 = *reinterpret_cast<const float4*>(&bias[nc0]);
    float4 bi1 = *reinterpret_cast<const float4*>(&bias[nc1]);
    float bb[8] = {bi0.x, bi0.y, bi0.z, bi0.w, bi1.x, bi1.y, bi1.z, bi1.w};
    float ex[8] = {};
    if (EPI == 2) {
        float4 e0 = *reinterpret_cast<const float4*>(&extra[nc0]);
        float4 e1 = *reinterpret_cast<const float4*>(&extra[nc1]);
        ex[0] = e0.x; ex[1] = e0.y; ex[2] = e0.z; ex[3] = e0.w;
        ex[4] = e1.x; ex[5] = e1.y; ex[6] = e1.z; ex[7] = e1.w;
    }
#pragma unroll
    for (int i = 0; i < 16; ++i) {
        int m = m0 + ty * 16 + i;
        float o[8];
#pragma unroll
        for (int j = 0; j < 8; ++j) {
            float v = acc[i][j] + bb[j];
            if (EPI == 1) v = v / (1.f + expf(-v));                // silu
            if (EPI == 2) {                                        // softplus(extra+v)
                float t2 = ex[j] + v;
                v = fmaxf(t2, 0.f) + log1pf(expf(-fabsf(t2)));
            }
            o[j] = v;
        }
        float4 o0 = {o[0], o[1], o[2], o[3]};
        float4 o1 = {o[4], o[5], o[6], o[7]};
        *reinterpret_cast<float4*>(&C[(size_t)m * N + nc0]) = o0;
        *reinterpret_cast<float4*>(&C[(size_t)m * N + nc1]) = o1;
    }
}

// ---------------------------------------------------------------------------
// depthwise causal conv (K=4) + bias + silu; also writes a[..., 1:] output
// ---------------------------------------------------------------------------
__global__ __launch_bounds__(256) void conv_k(
    const float* __restrict__ apre, const float* __restrict__ cw,
    const float* __restrict__ cb, float* __restrict__ aout,
    float* __restrict__ trim)
{
    int idx = blockIdx.x * 256 + threadIdx.x;          // (b*L + t)*H + d
    int d  = idx % H_DIM;
    int bt = idx / H_DIM;
    int t  = bt % LSEQ;

    float4 w = *reinterpret_cast<const float4*>(cw + (size_t)d * KW);
    float acc = cb[d];
    if (t >= KW - 1) {
        const float* base = apre + (size_t)(bt - 3) * H_DIM + d;
        acc += base[0] * w.x;
        acc += base[H_DIM] * w.y;
        acc += base[2 * H_DIM] * w.z;
        acc += base[3 * H_DIM] * w.w;
    } else {
        const float* wp = reinterpret_cast<const float*>(&w);
#pragma unroll
        for (int j = 0; j < KW; ++j) {
            int tt = t + j - (KW - 1);
            if (tt >= 0) acc += apre[(size_t)(bt + j - 3) * H_DIM + d] * wp[j];
        }
    }
    float sv = acc / (1.f + expf(-acc));               // silu
    aout[idx] = sv;
    if (d >= 1)
        __builtin_nontemporal_store(sv, &trim[(size_t)bt * (H_DIM - 1) + d - 1]);
}

// ---------------------------------------------------------------------------
// Bm = a @ WB + bB   (skinny N=16)
// ---------------------------------------------------------------------------
__global__ __launch_bounds__(256) void bm_k(
    const float* __restrict__ a, const float* __restrict__ WB,
    const float* __restrict__ bB, float* __restrict__ Bm)
{
    int g = blockIdx.x * 256 + threadIdx.x;            // row*16 + n
    int row = g >> 4, n = g & 15;
    const float* ar = a + (size_t)row * H_DIM;
    float a0 = 0.f, a1 = 0.f, a2 = 0.f, a3 = 0.f;
    for (int k = 0; k < H_DIM; k += 4) {
        a0 = fmaf(ar[k],     WB[(size_t)(k)*DST + n],     a0);
        a1 = fmaf(ar[k + 1], WB[(size_t)(k + 1)*DST + n], a1);
        a2 = fmaf(ar[k + 2], WB[(size_t)(k + 2)*DST + n], a2);
        a3 = fmaf(ar[k + 3], WB[(size_t)(k + 3)*DST + n], a3);
    }
    Bm[g] = bB[n] + ((a0 + a1) + (a2 + a3));
}

// ---------------------------------------------------------------------------
// chunked selective scan:  h_t = (e^{-A} * delta_t) * h_{t-1} + Bm_t*delta_t*a_t
// Intermediates hend/P/Hinit laid out [(b*CCH + c)*HS + ds] (coalesced in ds).
// ---------------------------------------------------------------------------
__global__ __launch_bounds__(256) void scan_a(
    const float* __restrict__ delta, const float* __restrict__ a,
    const float* __restrict__ Bm, const float* __restrict__ A,
    float* __restrict__ hend, float* __restrict__ Pout)
{
    int gtid = blockIdx.x * 256 + threadIdx.x;         // B*CCH*HS
    int ds = gtid % HS;
    int bc = gtid / HS;
    int c = bc % CCH, b = bc / CCH;
    int d = ds >> 4, s = ds & 15;

    float eA = expf(-A[ds]);
    float h = 0.f, P = 1.f;
    int bt0 = b * LSEQ + c * CLEN;
#pragma unroll 4
    for (int i = 0; i < CLEN; ++i) {
        int bt = bt0 + i;
        size_t ix = (size_t)bt * H_DIM + d;
        float dl = delta[ix];
        float av = a[ix];
        float bm = Bm[(size_t)bt * DST + s];
        float at = eA * dl;
        h = fmaf(at, h, bm * dl * av);
        P *= at;
    }
    size_t o = ((size_t)b * CCH + c) * HS + ds;
    hend[o] = h;
    Pout[o] = P;
}

__global__ __launch_bounds__(256) void scan_b(
    const float* __restrict__ hend, const float* __restrict__ P,
    float* __restrict__ Hinit)
{
    int gtid = blockIdx.x * 256 + threadIdx.x;         // B*HS
    int ds = gtid % HS;
    int b  = gtid / HS;
    float Hc = 0.f;
    for (int c = 0; c < CCH; ++c) {
        size_t o = ((size_t)b * CCH + c) * HS + ds;
        Hinit[o] = Hc;
        Hc = hend[o] + P[o] * Hc;
    }
}

__global__ __launch_bounds__(256) void scan_c(
    const float* __restrict__ delta, const float* __restrict__ a,
    const float* __restrict__ Bm, const float* __restrict__ A,
    const float* __restrict__ Hinit, float* __restrict__ hid)
{
    int gtid = blockIdx.x * 256 + threadIdx.x;
    int ds = gtid % HS;
    int bc = gtid / HS;
    int c = bc % CCH, b = bc / CCH;
    int d = ds >> 4, s = ds & 15;

    float eA = expf(-A[ds]);
    float h = Hinit[((size_t)b * CCH + c) * HS + ds];
    int bt0 = b * LSEQ + c * CLEN;
#pragma unroll 4
    for (int i = 0; i < CLEN; ++i) {
        int bt = bt0 + i;
        size_t ix = (size_t)bt * H_DIM + d;
        float dl = delta[ix];
        float av = a[ix];
        float bm = Bm[(size_t)bt * DST + s];
        float at = eA * dl;
        h = fmaf(at, h, bm * dl * av);
        // hid is written once, never re-read on device: stream past the caches
        __builtin_nontemporal_store(h, &hid[(size_t)bt * HS + ds]);
    }
}

// ---------------------------------------------------------------------------
extern "C" void kernel_launch(void* const* d_in, const int* in_sizes, int n_in,
                              void* d_out, int out_size, void* d_ws, size_t ws_size,
                              hipStream_t stream)
{
    const float* x      = (const float*)d_in[0];
    const float* W1     = (const float*)d_in[1];
    const float* b1     = (const float*)d_in[2];
    const float* W2     = (const float*)d_in[3];
    const float* b2     = (const float*)d_in[4];
    const float* conv_w = (const float*)d_in[5];
    const float* conv_b = (const float*)d_in[6];
    const float* Wf     = (const float*)d_in[7];
    const float* bf     = (const float*)d_in[8];
    const float* A      = (const float*)d_in[9];
    const float* WB     = (const float*)d_in[10];
    const float* bB     = (const float*)d_in[11];
    // d_in[12] = WC, d_in[13] = bC : unused by the reference's returned outputs
    const float* WD     = (const float*)d_in[14];
    const float* bD     = (const float*)d_in[15];
    const float* Dvec   = (const float*)d_in[16];

    float* out = (float*)d_out;
    // output layout: [output 4096*768][hid 4096*24576][trim 4096*1535]
    constexpr size_t OUT_HID  = (size_t)MROWS * DIM;
    constexpr size_t OUT_TRIM = OUT_HID + (size_t)MROWS * HS;
    float* out_y    = out;
    float* out_hid  = out + OUT_HID;
    float* out_trim = out + OUT_TRIM;

    // scratch inside the (not-yet-written) hid region of d_out:
    float* a_pre = out_hid;                                        // 6,291,456 f
    float* g     = out_hid + (size_t)MROWS * H_DIM;                // 6,291,456 f

    // workspace layout (floats): a(6.29M) delta(6.29M) Bm(64K) hend/P/Hinit(3x768K)
    float* ws      = (float*)d_ws;
    float* a_ws    = ws;
    float* delta   = a_ws  + (size_t)MROWS * H_DIM;
    float* Bm      = delta + (size_t)MROWS * H_DIM;
    float* hend    = Bm    + (size_t)MROWS * DST;
    float* Pprod   = hend  + (size_t)B_SZ * HS * CCH;
    float* Hinit   = Pprod + (size_t)B_SZ * HS * CCH;

    dim3 gblk(128);
    dim3 blk(256);

    // 1) a_pre = x@W1 + b1            [4096 x 1536, K=768]
    gemm_big<0, false><<<dim3(H_DIM / TBN, MROWS / TBM), gblk, 0, stream>>>(
        x, nullptr, W1, b1, nullptr, a_pre, MROWS, H_DIM, DIM);
    // 2) g = silu(x@W2 + b2)          [4096 x 1536, K=768]
    gemm_big<1, false><<<dim3(H_DIM / TBN, MROWS / TBM), gblk, 0, stream>>>(
        x, nullptr, W2, b2, nullptr, g, MROWS, H_DIM, DIM);
    // 3) a = silu(causal depthwise conv(a_pre)); also writes a[...,1:] output
    conv_k<<<(MROWS * H_DIM) / 256, blk, 0, stream>>>(a_pre, conv_w, conv_b, a_ws, out_trim);
    // 4) delta = softplus(Dvec + a@WD + bD)   [4096 x 1536, K=1536]
    gemm_big<2, false><<<dim3(H_DIM / TBN, MROWS / TBM), gblk, 0, stream>>>(
        a_ws, nullptr, WD, bD, Dvec, delta, MROWS, H_DIM, H_DIM);
    // 5) Bm = a@WB + bB
    bm_k<<<(MROWS * DST) / 256, blk, 0, stream>>>(a_ws, WB, bB, Bm);
    // 6) output = (a*g)@Wf + bf  [4096 x 768, K=1536; fused a*g in loader]
    gemm_big<0, true><<<dim3(DIM / TBN, MROWS / TBM), gblk, 0, stream>>>(
        a_ws, g, Wf, bf, nullptr, out_y, MROWS, DIM, H_DIM);
    // 7-9) chunked selective scan -> hid
    scan_a<<<(B_SZ * CCH * HS) / 256, blk, 0, stream>>>(delta, a_ws, Bm, A, hend, Pprod);
    scan_b<<<(B_SZ * HS) / 256, blk, 0, stream>>>(hend, Pprod, Hinit);
    scan_c<<<(B_SZ * CCH * HS) / 256, blk, 0, stream>>>(delta, a_ws, Bm, A, Hinit, out_hid);
}

// Round 6
// 1270.497 us; speedup vs baseline: 1.6093x; 1.6093x over previous
//
#include <hip/hip_runtime.h>
#include <hip/hip_bf16.h>
#include <cstddef>

// Problem constants (match reference)
constexpr int B_SZ  = 2;
constexpr int LSEQ  = 2048;
constexpr int DIM   = 768;
constexpr int H_DIM = 1536;
constexpr int DST   = 16;      // D_STATE
constexpr int KW    = 4;       // conv kernel width
constexpr int MROWS = B_SZ * LSEQ;        // 4096
constexpr int HS    = H_DIM * DST;        // 24576

// chunked scan config
constexpr int CCH  = 16;                  // chunks
constexpr int CLEN = LSEQ / CCH;          // 128

// ===========================================================================
// fp32 GEMM: 64x64 tile, 256 threads (4 waves), 4x4 acc/thread.
// Occupancy-first design (round-5 PMC: 128-thr/384-block variant was
// grid-starved: Occupancy 6.9%, VALUBusy 24.5%). Grid here = 1536 blocks
// (N=1536) -> 6 blocks/CU = 24 waves/CU. DS pipe per wave per kk:
// A-frag ~1 clk (broadcast) + B-frag ~2 clk vs 32 FMA SIMD-cycles -> VALU-bound.
// C[M,N] = epi((A [*A2]) @ Bw + bias);  EPI: 0=none, 1=silu, 2=softplus(extra+v)
// ===========================================================================
#define GBM 64
#define GBN 64
#define GBK 16

template <int EPI, bool AMUL>
__global__ __launch_bounds__(256) void gemm_k(
    const float* __restrict__ A, const float* __restrict__ A2,
    const float* __restrict__ Bw, const float* __restrict__ bias,
    const float* __restrict__ extra, float* __restrict__ C,
    int M, int N, int Kd)
{
    __shared__ float As[GBK][GBM + 4];   // +4 pad: A-frag reads spread banks
    __shared__ float Bs[GBK][GBN];

    const int tid = threadIdx.x;
    const int n0 = blockIdx.x * GBN;
    const int m0 = blockIdx.y * GBM;
    const int tx = tid & 15;        // 16 col-groups -> cols tx*4..+3
    const int ty = tid >> 4;        // 16 row-groups -> rows ty*4..+3

    const int la_k = tid & 15;      // A loader: k within tile
    const int la_m = tid >> 4;      // A loader: row base (step 16)
    const int lb_n = tid & 63;      // B loader: col
    const int lb_k = tid >> 6;      // B loader: k base (step 4)

    float acc[4][4] = {};

    for (int k0 = 0; k0 < Kd; k0 += GBK) {
#pragma unroll
        for (int i = 0; i < 4; ++i) {
            int m = la_m + i * 16;
            size_t gi = (size_t)(m0 + m) * Kd + k0 + la_k;
            float v = A[gi];
            if (AMUL) v *= A2[gi];
            As[la_k][m] = v;
        }
#pragma unroll
        for (int i = 0; i < 4; ++i) {
            int kk = lb_k + i * 4;
            Bs[kk][lb_n] = Bw[(size_t)(k0 + kk) * N + n0 + lb_n];
        }
        __syncthreads();
#pragma unroll
        for (int kk = 0; kk < GBK; ++kk) {
            float4 a4 = *reinterpret_cast<const float4*>(&As[kk][ty * 4]);
            float4 b4 = *reinterpret_cast<const float4*>(&Bs[kk][tx * 4]);
            float av[4] = {a4.x, a4.y, a4.z, a4.w};
            float bv[4] = {b4.x, b4.y, b4.z, b4.w};
#pragma unroll
            for (int i = 0; i < 4; ++i)
#pragma unroll
                for (int j = 0; j < 4; ++j)
                    acc[i][j] = fmaf(av[i], bv[j], acc[i][j]);
        }
        __syncthreads();
    }

    // epilogue
    const int nc = n0 + tx * 4;
    float4 bia = *reinterpret_cast<const float4*>(&bias[nc]);
    float bb[4] = {bia.x, bia.y, bia.z, bia.w};
    float ex[4] = {0.f, 0.f, 0.f, 0.f};
    if (EPI == 2) {
        float4 e4 = *reinterpret_cast<const float4*>(&extra[nc]);
        ex[0] = e4.x; ex[1] = e4.y; ex[2] = e4.z; ex[3] = e4.w;
    }
#pragma unroll
    for (int i = 0; i < 4; ++i) {
        int m = m0 + ty * 4 + i;
        float o[4];
#pragma unroll
        for (int j = 0; j < 4; ++j) {
            float v = acc[i][j] + bb[j];
            if (EPI == 1) v = v / (1.f + expf(-v));                // silu
            if (EPI == 2) {                                        // softplus(extra+v)
                float t2 = ex[j] + v;
                v = fmaxf(t2, 0.f) + log1pf(expf(-fabsf(t2)));
            }
            o[j] = v;
        }
        float4 o4 = {o[0], o[1], o[2], o[3]};
        *reinterpret_cast<float4*>(&C[(size_t)m * N + nc]) = o4;
    }
}

// ---------------------------------------------------------------------------
// depthwise causal conv (K=4) + bias + silu; also writes a[..., 1:] output
// ---------------------------------------------------------------------------
__global__ __launch_bounds__(256) void conv_k(
    const float* __restrict__ apre, const float* __restrict__ cw,
    const float* __restrict__ cb, float* __restrict__ aout,
    float* __restrict__ trim)
{
    int idx = blockIdx.x * 256 + threadIdx.x;          // (b*L + t)*H + d
    int d  = idx % H_DIM;
    int bt = idx / H_DIM;
    int t  = bt % LSEQ;

    float4 w = *reinterpret_cast<const float4*>(cw + (size_t)d * KW);
    float acc = cb[d];
    if (t >= KW - 1) {
        const float* base = apre + (size_t)(bt - 3) * H_DIM + d;
        acc += base[0] * w.x;
        acc += base[H_DIM] * w.y;
        acc += base[2 * H_DIM] * w.z;
        acc += base[3 * H_DIM] * w.w;
    } else {
        const float* wp = reinterpret_cast<const float*>(&w);
#pragma unroll
        for (int j = 0; j < KW; ++j) {
            int tt = t + j - (KW - 1);
            if (tt >= 0) acc += apre[(size_t)(bt + j - 3) * H_DIM + d] * wp[j];
        }
    }
    float sv = acc / (1.f + expf(-acc));               // silu
    aout[idx] = sv;
    if (d >= 1)
        __builtin_nontemporal_store(sv, &trim[(size_t)bt * (H_DIM - 1) + d - 1]);
}

// ---------------------------------------------------------------------------
// Bm = a @ WB + bB   (skinny N=16)
// ---------------------------------------------------------------------------
__global__ __launch_bounds__(256) void bm_k(
    const float* __restrict__ a, const float* __restrict__ WB,
    const float* __restrict__ bB, float* __restrict__ Bm)
{
    int g = blockIdx.x * 256 + threadIdx.x;            // row*16 + n
    int row = g >> 4, n = g & 15;
    const float* ar = a + (size_t)row * H_DIM;
    float a0 = 0.f, a1 = 0.f, a2 = 0.f, a3 = 0.f;
    for (int k = 0; k < H_DIM; k += 4) {
        a0 = fmaf(ar[k],     WB[(size_t)(k)*DST + n],     a0);
        a1 = fmaf(ar[k + 1], WB[(size_t)(k + 1)*DST + n], a1);
        a2 = fmaf(ar[k + 2], WB[(size_t)(k + 2)*DST + n], a2);
        a3 = fmaf(ar[k + 3], WB[(size_t)(k + 3)*DST + n], a3);
    }
    Bm[g] = bB[n] + ((a0 + a1) + (a2 + a3));
}

// ---------------------------------------------------------------------------
// chunked selective scan:  h_t = (e^{-A} * delta_t) * h_{t-1} + Bm_t*delta_t*a_t
// Intermediates hend/P/Hinit laid out [(b*CCH + c)*HS + ds] (coalesced in ds).
// ---------------------------------------------------------------------------
__global__ __launch_bounds__(256) void scan_a(
    const float* __restrict__ delta, const float* __restrict__ a,
    const float* __restrict__ Bm, const float* __restrict__ A,
    float* __restrict__ hend, float* __restrict__ Pout)
{
    int gtid = blockIdx.x * 256 + threadIdx.x;         // B*CCH*HS
    int ds = gtid % HS;
    int bc = gtid / HS;
    int c = bc % CCH, b = bc / CCH;
    int d = ds >> 4, s = ds & 15;

    float eA = expf(-A[ds]);
    float h = 0.f, P = 1.f;
    int bt0 = b * LSEQ + c * CLEN;
#pragma unroll 4
    for (int i = 0; i < CLEN; ++i) {
        int bt = bt0 + i;
        size_t ix = (size_t)bt * H_DIM + d;
        float dl = delta[ix];
        float av = a[ix];
        float bm = Bm[(size_t)bt * DST + s];
        float at = eA * dl;
        h = fmaf(at, h, bm * dl * av);
        P *= at;
    }
    size_t o = ((size_t)b * CCH + c) * HS + ds;
    hend[o] = h;
    Pout[o] = P;
}

__global__ __launch_bounds__(256) void scan_b(
    const float* __restrict__ hend, const float* __restrict__ P,
    float* __restrict__ Hinit)
{
    int gtid = blockIdx.x * 256 + threadIdx.x;         // B*HS
    int ds = gtid % HS;
    int b  = gtid / HS;
    float Hc = 0.f;
    for (int c = 0; c < CCH; ++c) {
        size_t o = ((size_t)b * CCH + c) * HS + ds;
        Hinit[o] = Hc;
        Hc = hend[o] + P[o] * Hc;
    }
}

__global__ __launch_bounds__(256) void scan_c(
    const float* __restrict__ delta, const float* __restrict__ a,
    const float* __restrict__ Bm, const float* __restrict__ A,
    const float* __restrict__ Hinit, float* __restrict__ hid)
{
    int gtid = blockIdx.x * 256 + threadIdx.x;
    int ds = gtid % HS;
    int bc = gtid / HS;
    int c = bc % CCH, b = bc / CCH;
    int d = ds >> 4, s = ds & 15;

    float eA = expf(-A[ds]);
    float h = Hinit[((size_t)b * CCH + c) * HS + ds];
    int bt0 = b * LSEQ + c * CLEN;
#pragma unroll 4
    for (int i = 0; i < CLEN; ++i) {
        int bt = bt0 + i;
        size_t ix = (size_t)bt * H_DIM + d;
        float dl = delta[ix];
        float av = a[ix];
        float bm = Bm[(size_t)bt * DST + s];
        float at = eA * dl;
        h = fmaf(at, h, bm * dl * av);
        // hid is written once, never re-read on device: stream past the caches
        __builtin_nontemporal_store(h, &hid[(size_t)bt * HS + ds]);
    }
}

// ---------------------------------------------------------------------------
extern "C" void kernel_launch(void* const* d_in, const int* in_sizes, int n_in,
                              void* d_out, int out_size, void* d_ws, size_t ws_size,
                              hipStream_t stream)
{
    const float* x      = (const float*)d_in[0];
    const float* W1     = (const float*)d_in[1];
    const float* b1     = (const float*)d_in[2];
    const float* W2     = (const float*)d_in[3];
    const float* b2     = (const float*)d_in[4];
    const float* conv_w = (const float*)d_in[5];
    const float* conv_b = (const float*)d_in[6];
    const float* Wf     = (const float*)d_in[7];
    const float* bf     = (const float*)d_in[8];
    const float* A      = (const float*)d_in[9];
    const float* WB     = (const float*)d_in[10];
    const float* bB     = (const float*)d_in[11];
    // d_in[12] = WC, d_in[13] = bC : unused by the reference's returned outputs
    const float* WD     = (const float*)d_in[14];
    const float* bD     = (const float*)d_in[15];
    const float* Dvec   = (const float*)d_in[16];

    float* out = (float*)d_out;
    // output layout: [output 4096*768][hid 4096*24576][trim 4096*1535]
    constexpr size_t OUT_HID  = (size_t)MROWS * DIM;
    constexpr size_t OUT_TRIM = OUT_HID + (size_t)MROWS * HS;
    float* out_y    = out;
    float* out_hid  = out + OUT_HID;
    float* out_trim = out + OUT_TRIM;

    // scratch inside the (not-yet-written) hid region of d_out:
    float* a_pre = out_hid;                                        // 6,291,456 f
    float* g     = out_hid + (size_t)MROWS * H_DIM;                // 6,291,456 f

    // workspace layout (floats): a(6.29M) delta(6.29M) Bm(64K) hend/P/Hinit(3x768K)
    float* ws      = (float*)d_ws;
    float* a_ws    = ws;
    float* delta   = a_ws  + (size_t)MROWS * H_DIM;
    float* Bm      = delta + (size_t)MROWS * H_DIM;
    float* hend    = Bm    + (size_t)MROWS * DST;
    float* Pprod   = hend  + (size_t)B_SZ * HS * CCH;
    float* Hinit   = Pprod + (size_t)B_SZ * HS * CCH;

    dim3 blk(256);

    // 1) a_pre = x@W1 + b1            [4096 x 1536, K=768] grid 24x64=1536
    gemm_k<0, false><<<dim3(H_DIM / GBN, MROWS / GBM), blk, 0, stream>>>(
        x, nullptr, W1, b1, nullptr, a_pre, MROWS, H_DIM, DIM);
    // 2) g = silu(x@W2 + b2)          [4096 x 1536, K=768]
    gemm_k<1, false><<<dim3(H_DIM / GBN, MROWS / GBM), blk, 0, stream>>>(
        x, nullptr, W2, b2, nullptr, g, MROWS, H_DIM, DIM);
    // 3) a = silu(causal depthwise conv(a_pre)); also writes a[...,1:] output
    conv_k<<<(MROWS * H_DIM) / 256, blk, 0, stream>>>(a_pre, conv_w, conv_b, a_ws, out_trim);
    // 4) delta = softplus(Dvec + a@WD + bD)   [4096 x 1536, K=1536]
    gemm_k<2, false><<<dim3(H_DIM / GBN, MROWS / GBM), blk, 0, stream>>>(
        a_ws, nullptr, WD, bD, Dvec, delta, MROWS, H_DIM, H_DIM);
    // 5) Bm = a@WB + bB
    bm_k<<<(MROWS * DST) / 256, blk, 0, stream>>>(a_ws, WB, bB, Bm);
    // 6) output = (a*g)@Wf + bf  [4096 x 768, K=1536; fused a*g; grid 12x64]
    gemm_k<0, true><<<dim3(DIM / GBN, MROWS / GBM), blk, 0, stream>>>(
        a_ws, g, Wf, bf, nullptr, out_y, MROWS, DIM, H_DIM);
    // 7-9) chunked selective scan -> hid
    scan_a<<<(B_SZ * CCH * HS) / 256, blk, 0, stream>>>(delta, a_ws, Bm, A, hend, Pprod);
    scan_b<<<(B_SZ * HS) / 256, blk, 0, stream>>>(hend, Pprod, Hinit);
    scan_c<<<(B_SZ * CCH * HS) / 256, blk, 0, stream>>>(delta, a_ws, Bm, A, Hinit, out_hid);
}

// Round 7
// 940.969 us; speedup vs baseline: 2.1729x; 1.3502x over previous
//
#include <hip/hip_runtime.h>
#include <hip/hip_bf16.h>
#include <cstddef>

// Problem constants (match reference)
constexpr int B_SZ  = 2;
constexpr int LSEQ  = 2048;
constexpr int DIM   = 768;
constexpr int H_DIM = 1536;
constexpr int DST   = 16;      // D_STATE
constexpr int KW    = 4;       // conv kernel width
constexpr int MROWS = B_SZ * LSEQ;        // 4096
constexpr int HS    = H_DIM * DST;        // 24576

// chunked scan config
constexpr int CCH  = 16;                  // chunks
constexpr int CLEN = LSEQ / CCH;          // 128

using short8 = __attribute__((ext_vector_type(8))) short;
using f32x4  = __attribute__((ext_vector_type(4))) float;

// fp32 -> bf16 (RNE) and back, via bit ops (inputs are finite/well-scaled)
__device__ __forceinline__ short f2bf(float v) {
    union { float f; unsigned u; } x; x.f = v;
    unsigned r = (x.u + 0x7FFFu + ((x.u >> 16) & 1u)) >> 16;
    return (short)r;
}
__device__ __forceinline__ float bf2f(short s) {
    union { unsigned u; float f; } x; x.u = ((unsigned)(unsigned short)s) << 16;
    return x.f;
}

// ===========================================================================
// Weight transpose + bf16x2 split: W[K][N] fp32 -> Wh[N][K], Wl[N][K] bf16.
// Run once per launch; total ~24 MB -> ~10 us. 32x32 LDS tile.
// ===========================================================================
__global__ __launch_bounds__(256) void wsplit_k(
    const float* __restrict__ W, unsigned short* __restrict__ Wh,
    unsigned short* __restrict__ Wl, int K, int N)
{
    __shared__ float t[32][33];
    const int k0 = blockIdx.x * 32, n0 = blockIdx.y * 32;
    const int r = threadIdx.x >> 5, c = threadIdx.x & 31;
#pragma unroll
    for (int p = 0; p < 4; ++p)
        t[r + p * 8][c] = W[(size_t)(k0 + r + p * 8) * N + n0 + c];
    __syncthreads();
#pragma unroll
    for (int p = 0; p < 4; ++p) {
        int rr = r + p * 8;                       // n-offset in tile
        float v = t[c][rr];                       // = W[k0+c][n0+rr]
        short hi = f2bf(v);
        short lo = f2bf(v - bf2f(hi));
        size_t o = (size_t)(n0 + rr) * K + k0 + c;
        Wh[o] = (unsigned short)hi;
        Wl[o] = (unsigned short)lo;
    }
}

// ===========================================================================
// bf16x2 emulated-fp32 GEMM on matrix cores.
// C[M,N] = epi((A [*A2]) @ B + bias), B pre-split/transposed as Bh/Bl [N][K].
// a*b ~= ah*bh + ah*bl + al*bh  (drop ll: rel err ~1e-5).
// Tile 128x128, BK=32, 256 thr = 4 waves (2x2), wave = 4x4 frags of
// mfma_f32_16x16x32_bf16. C/D layout: col=lane&15, row=(lane>>4)*4+reg [m89].
// A-frag: row=lane&15, k=(lane>>4)*8+i  -> LDS [row][k], stride 40 shorts
// (16B-aligned rows; rows cycle 8 distinct 4-bank groups -> <=2-way conflict).
// ===========================================================================
template <int EPI, bool AMUL>
__global__ __launch_bounds__(256) void gemm_mx(
    const float* __restrict__ A, const float* __restrict__ A2,
    const unsigned short* __restrict__ WBh, const unsigned short* __restrict__ WBl,
    const float* __restrict__ bias, const float* __restrict__ extra,
    float* __restrict__ C, int M, int N, int K)
{
    constexpr int SK = 40;                        // padded k-stride (shorts)
    __shared__ short Ah[128 * SK], Al[128 * SK];
    __shared__ short Bh[128 * SK], Bl[128 * SK];

    const int tid  = threadIdx.x;
    const int n0   = blockIdx.x * 128, m0 = blockIdx.y * 128;
    const int wave = tid >> 6, lane = tid & 63;
    const int wm   = wave >> 1, wn = wave & 1;    // 2x2 wave grid, 64x64 each
    const int lr   = lane & 15, kg = lane >> 4;

    const int srow = tid >> 1;                    // staging row (0..127)
    const int skh  = (tid & 1) * 16;              // staging k-half

    f32x4 acc[4][4] = {};

    for (int k0 = 0; k0 < K; k0 += 32) {
        // ---- stage A: fp32 -> (hi,lo) bf16 on the fly
        {
            const float* ap = A + (size_t)(m0 + srow) * K + k0 + skh;
            float va[16];
            *reinterpret_cast<float4*>(&va[0])  = *reinterpret_cast<const float4*>(ap + 0);
            *reinterpret_cast<float4*>(&va[4])  = *reinterpret_cast<const float4*>(ap + 4);
            *reinterpret_cast<float4*>(&va[8])  = *reinterpret_cast<const float4*>(ap + 8);
            *reinterpret_cast<float4*>(&va[12]) = *reinterpret_cast<const float4*>(ap + 12);
            if (AMUL) {
                const float* gp = A2 + (size_t)(m0 + srow) * K + k0 + skh;
                float vg[16];
                *reinterpret_cast<float4*>(&vg[0])  = *reinterpret_cast<const float4*>(gp + 0);
                *reinterpret_cast<float4*>(&vg[4])  = *reinterpret_cast<const float4*>(gp + 4);
                *reinterpret_cast<float4*>(&vg[8])  = *reinterpret_cast<const float4*>(gp + 8);
                *reinterpret_cast<float4*>(&vg[12]) = *reinterpret_cast<const float4*>(gp + 12);
#pragma unroll
                for (int i = 0; i < 16; ++i) va[i] *= vg[i];
            }
            short sh[16], sl[16];
#pragma unroll
            for (int i = 0; i < 16; ++i) {
                sh[i] = f2bf(va[i]);
                sl[i] = f2bf(va[i] - bf2f(sh[i]));
            }
            int ab = srow * SK + skh;
            *reinterpret_cast<short8*>(&Ah[ab + 0]) = *reinterpret_cast<short8*>(&sh[0]);
            *reinterpret_cast<short8*>(&Ah[ab + 8]) = *reinterpret_cast<short8*>(&sh[8]);
            *reinterpret_cast<short8*>(&Al[ab + 0]) = *reinterpret_cast<short8*>(&sl[0]);
            *reinterpret_cast<short8*>(&Al[ab + 8]) = *reinterpret_cast<short8*>(&sl[8]);
        }
        // ---- stage B: pre-split bf16, straight copies
        {
            size_t bo = (size_t)(n0 + srow) * K + k0 + skh;
            int bb = srow * SK + skh;
            *reinterpret_cast<short8*>(&Bh[bb + 0]) = *reinterpret_cast<const short8*>(WBh + bo);
            *reinterpret_cast<short8*>(&Bh[bb + 8]) = *reinterpret_cast<const short8*>(WBh + bo + 8);
            *reinterpret_cast<short8*>(&Bl[bb + 0]) = *reinterpret_cast<const short8*>(WBl + bo);
            *reinterpret_cast<short8*>(&Bl[bb + 8]) = *reinterpret_cast<const short8*>(WBl + bo + 8);
        }
        __syncthreads();

        short8 fa_h[4], fa_l[4], fb_h[4], fb_l[4];
#pragma unroll
        for (int f = 0; f < 4; ++f) {
            int aoff = (wm * 64 + f * 16 + lr) * SK + kg * 8;
            int boff = (wn * 64 + f * 16 + lr) * SK + kg * 8;
            fa_h[f] = *reinterpret_cast<const short8*>(&Ah[aoff]);
            fa_l[f] = *reinterpret_cast<const short8*>(&Al[aoff]);
            fb_h[f] = *reinterpret_cast<const short8*>(&Bh[boff]);
            fb_l[f] = *reinterpret_cast<const short8*>(&Bl[boff]);
        }
        // 3 passes: same-acc MFMAs spaced 16 apart (hide MFMA latency)
#pragma unroll
        for (int mf = 0; mf < 4; ++mf)
#pragma unroll
            for (int nf = 0; nf < 4; ++nf)
                acc[mf][nf] = __builtin_amdgcn_mfma_f32_16x16x32_bf16(
                    fa_h[mf], fb_h[nf], acc[mf][nf], 0, 0, 0);
#pragma unroll
        for (int mf = 0; mf < 4; ++mf)
#pragma unroll
            for (int nf = 0; nf < 4; ++nf)
                acc[mf][nf] = __builtin_amdgcn_mfma_f32_16x16x32_bf16(
                    fa_h[mf], fb_l[nf], acc[mf][nf], 0, 0, 0);
#pragma unroll
        for (int mf = 0; mf < 4; ++mf)
#pragma unroll
            for (int nf = 0; nf < 4; ++nf)
                acc[mf][nf] = __builtin_amdgcn_mfma_f32_16x16x32_bf16(
                    fa_l[mf], fb_h[nf], acc[mf][nf], 0, 0, 0);
        __syncthreads();
    }

    // ---- epilogue
    float bv[4], ev[4];
#pragma unroll
    for (int nf = 0; nf < 4; ++nf) {
        int col = n0 + wn * 64 + nf * 16 + lr;
        bv[nf] = bias[col];
        ev[nf] = (EPI == 2) ? extra[col] : 0.f;
    }
#pragma unroll
    for (int mf = 0; mf < 4; ++mf)
#pragma unroll
        for (int nf = 0; nf < 4; ++nf) {
            int col = n0 + wn * 64 + nf * 16 + lr;
#pragma unroll
            for (int r = 0; r < 4; ++r) {
                int mrow = m0 + wm * 64 + mf * 16 + kg * 4 + r;
                float v = acc[mf][nf][r] + bv[nf];
                if (EPI == 1) v = v / (1.f + expf(-v));            // silu
                if (EPI == 2) {                                    // softplus(extra+v)
                    float t2 = ev[nf] + v;
                    v = fmaxf(t2, 0.f) + log1pf(expf(-fabsf(t2)));
                }
                C[(size_t)mrow * N + col] = v;
            }
        }
}

// ---------------------------------------------------------------------------
// depthwise causal conv (K=4) + bias + silu; also writes a[..., 1:] output
// ---------------------------------------------------------------------------
__global__ __launch_bounds__(256) void conv_k(
    const float* __restrict__ apre, const float* __restrict__ cw,
    const float* __restrict__ cb, float* __restrict__ aout,
    float* __restrict__ trim)
{
    int idx = blockIdx.x * 256 + threadIdx.x;          // (b*L + t)*H + d
    int d  = idx % H_DIM;
    int bt = idx / H_DIM;
    int t  = bt % LSEQ;

    float4 w = *reinterpret_cast<const float4*>(cw + (size_t)d * KW);
    float acc = cb[d];
    if (t >= KW - 1) {
        const float* base = apre + (size_t)(bt - 3) * H_DIM + d;
        acc += base[0] * w.x;
        acc += base[H_DIM] * w.y;
        acc += base[2 * H_DIM] * w.z;
        acc += base[3 * H_DIM] * w.w;
    } else {
        const float* wp = reinterpret_cast<const float*>(&w);
#pragma unroll
        for (int j = 0; j < KW; ++j) {
            int tt = t + j - (KW - 1);
            if (tt >= 0) acc += apre[(size_t)(bt + j - 3) * H_DIM + d] * wp[j];
        }
    }
    float sv = acc / (1.f + expf(-acc));               // silu
    aout[idx] = sv;
    if (d >= 1)
        __builtin_nontemporal_store(sv, &trim[(size_t)bt * (H_DIM - 1) + d - 1]);
}

// ---------------------------------------------------------------------------
// Bm = a @ WB + bB   (skinny N=16)
// ---------------------------------------------------------------------------
__global__ __launch_bounds__(256) void bm_k(
    const float* __restrict__ a, const float* __restrict__ WB,
    const float* __restrict__ bB, float* __restrict__ Bm)
{
    int g = blockIdx.x * 256 + threadIdx.x;            // row*16 + n
    int row = g >> 4, n = g & 15;
    const float* ar = a + (size_t)row * H_DIM;
    float a0 = 0.f, a1 = 0.f, a2 = 0.f, a3 = 0.f;
    for (int k = 0; k < H_DIM; k += 4) {
        a0 = fmaf(ar[k],     WB[(size_t)(k)*DST + n],     a0);
        a1 = fmaf(ar[k + 1], WB[(size_t)(k + 1)*DST + n], a1);
        a2 = fmaf(ar[k + 2], WB[(size_t)(k + 2)*DST + n], a2);
        a3 = fmaf(ar[k + 3], WB[(size_t)(k + 3)*DST + n], a3);
    }
    Bm[g] = bB[n] + ((a0 + a1) + (a2 + a3));
}

// ---------------------------------------------------------------------------
// chunked selective scan:  h_t = (e^{-A} * delta_t) * h_{t-1} + Bm_t*delta_t*a_t
// Intermediates hend/P/Hinit laid out [(b*CCH + c)*HS + ds] (coalesced in ds).
// ---------------------------------------------------------------------------
__global__ __launch_bounds__(256) void scan_a(
    const float* __restrict__ delta, const float* __restrict__ a,
    const float* __restrict__ Bm, const float* __restrict__ A,
    float* __restrict__ hend, float* __restrict__ Pout)
{
    int gtid = blockIdx.x * 256 + threadIdx.x;         // B*CCH*HS
    int ds = gtid % HS;
    int bc = gtid / HS;
    int c = bc % CCH, b = bc / CCH;
    int d = ds >> 4, s = ds & 15;

    float eA = expf(-A[ds]);
    float h = 0.f, P = 1.f;
    int bt0 = b * LSEQ + c * CLEN;
#pragma unroll 4
    for (int i = 0; i < CLEN; ++i) {
        int bt = bt0 + i;
        size_t ix = (size_t)bt * H_DIM + d;
        float dl = delta[ix];
        float av = a[ix];
        float bm = Bm[(size_t)bt * DST + s];
        float at = eA * dl;
        h = fmaf(at, h, bm * dl * av);
        P *= at;
    }
    size_t o = ((size_t)b * CCH + c) * HS + ds;
    hend[o] = h;
    Pout[o] = P;
}

__global__ __launch_bounds__(256) void scan_b(
    const float* __restrict__ hend, const float* __restrict__ P,
    float* __restrict__ Hinit)
{
    int gtid = blockIdx.x * 256 + threadIdx.x;         // B*HS
    int ds = gtid % HS;
    int b  = gtid / HS;
    float Hc = 0.f;
    for (int c = 0; c < CCH; ++c) {
        size_t o = ((size_t)b * CCH + c) * HS + ds;
        Hinit[o] = Hc;
        Hc = hend[o] + P[o] * Hc;
    }
}

__global__ __launch_bounds__(256) void scan_c(
    const float* __restrict__ delta, const float* __restrict__ a,
    const float* __restrict__ Bm, const float* __restrict__ A,
    const float* __restrict__ Hinit, float* __restrict__ hid)
{
    int gtid = blockIdx.x * 256 + threadIdx.x;
    int ds = gtid % HS;
    int bc = gtid / HS;
    int c = bc % CCH, b = bc / CCH;
    int d = ds >> 4, s = ds & 15;

    float eA = expf(-A[ds]);
    float h = Hinit[((size_t)b * CCH + c) * HS + ds];
    int bt0 = b * LSEQ + c * CLEN;
#pragma unroll 4
    for (int i = 0; i < CLEN; ++i) {
        int bt = bt0 + i;
        size_t ix = (size_t)bt * H_DIM + d;
        float dl = delta[ix];
        float av = a[ix];
        float bm = Bm[(size_t)bt * DST + s];
        float at = eA * dl;
        h = fmaf(at, h, bm * dl * av);
        // hid is written once, never re-read on device: stream past the caches
        __builtin_nontemporal_store(h, &hid[(size_t)bt * HS + ds]);
    }
}

// ---------------------------------------------------------------------------
extern "C" void kernel_launch(void* const* d_in, const int* in_sizes, int n_in,
                              void* d_out, int out_size, void* d_ws, size_t ws_size,
                              hipStream_t stream)
{
    const float* x      = (const float*)d_in[0];
    const float* W1     = (const float*)d_in[1];
    const float* b1     = (const float*)d_in[2];
    const float* W2     = (const float*)d_in[3];
    const float* b2     = (const float*)d_in[4];
    const float* conv_w = (const float*)d_in[5];
    const float* conv_b = (const float*)d_in[6];
    const float* Wf     = (const float*)d_in[7];
    const float* bf     = (const float*)d_in[8];
    const float* A      = (const float*)d_in[9];
    const float* WB     = (const float*)d_in[10];
    const float* bB     = (const float*)d_in[11];
    // d_in[12] = WC, d_in[13] = bC : unused by the reference's returned outputs
    const float* WD     = (const float*)d_in[14];
    const float* bD     = (const float*)d_in[15];
    const float* Dvec   = (const float*)d_in[16];

    float* out = (float*)d_out;
    // output layout: [output 4096*768][hid 4096*24576][trim 4096*1535]
    constexpr size_t OUT_HID  = (size_t)MROWS * DIM;
    constexpr size_t OUT_TRIM = OUT_HID + (size_t)MROWS * HS;
    float* out_y    = out;
    float* out_hid  = out + OUT_HID;
    float* out_trim = out + OUT_TRIM;

    // scratch inside the (not-yet-written) hid region of d_out (402 MB):
    constexpr size_t MH = (size_t)MROWS * H_DIM;                   // 6,291,456
    float* a_pre = out_hid;                                        // [MH]
    float* g     = out_hid + MH;                                   // [MH]
    // bf16x2 split weights (hi/lo, transposed to [N][K]) after a_pre/g:
    unsigned short* wsp = (unsigned short*)(out_hid + 2 * MH);
    constexpr size_t WSMALL = (size_t)H_DIM * DIM;                 // 1,179,648
    constexpr size_t WBIG   = (size_t)H_DIM * H_DIM;               // 2,359,296
    unsigned short* W1h = wsp;
    unsigned short* W1l = W1h + WSMALL;
    unsigned short* W2h = W1l + WSMALL;
    unsigned short* W2l = W2h + WSMALL;
    unsigned short* WDh = W2l + WSMALL;
    unsigned short* WDl = WDh + WBIG;
    unsigned short* Wfh = WDl + WBIG;
    unsigned short* Wfl = Wfh + WSMALL;
    // total: 11.8M shorts = 23.6 MB; all dead before scan_c overwrites hid.

    // workspace layout (floats): a(6.29M) delta(6.29M) Bm(64K) hend/P/Hinit(3x768K)
    float* ws      = (float*)d_ws;
    float* a_ws    = ws;
    float* delta   = a_ws  + MH;
    float* Bm      = delta + MH;
    float* hend    = Bm    + (size_t)MROWS * DST;
    float* Pprod   = hend  + (size_t)B_SZ * HS * CCH;
    float* Hinit   = Pprod + (size_t)B_SZ * HS * CCH;

    dim3 blk(256);

    // 0) weight transpose + bf16x2 split (runs every launch; ~10 us total)
    wsplit_k<<<dim3(DIM / 32, H_DIM / 32), blk, 0, stream>>>(W1, W1h, W1l, DIM, H_DIM);
    wsplit_k<<<dim3(DIM / 32, H_DIM / 32), blk, 0, stream>>>(W2, W2h, W2l, DIM, H_DIM);
    wsplit_k<<<dim3(H_DIM / 32, H_DIM / 32), blk, 0, stream>>>(WD, WDh, WDl, H_DIM, H_DIM);
    wsplit_k<<<dim3(H_DIM / 32, DIM / 32), blk, 0, stream>>>(Wf, Wfh, Wfl, H_DIM, DIM);

    // 1) a_pre = x@W1 + b1            [4096 x 1536, K=768]
    gemm_mx<0, false><<<dim3(H_DIM / 128, MROWS / 128), blk, 0, stream>>>(
        x, nullptr, W1h, W1l, b1, nullptr, a_pre, MROWS, H_DIM, DIM);
    // 2) g = silu(x@W2 + b2)
    gemm_mx<1, false><<<dim3(H_DIM / 128, MROWS / 128), blk, 0, stream>>>(
        x, nullptr, W2h, W2l, b2, nullptr, g, MROWS, H_DIM, DIM);
    // 3) a = silu(causal depthwise conv(a_pre)); also writes a[...,1:] output
    conv_k<<<(MROWS * H_DIM) / 256, blk, 0, stream>>>(a_pre, conv_w, conv_b, a_ws, out_trim);
    // 4) delta = softplus(Dvec + a@WD + bD)   [4096 x 1536, K=1536]
    gemm_mx<2, false><<<dim3(H_DIM / 128, MROWS / 128), blk, 0, stream>>>(
        a_ws, nullptr, WDh, WDl, bD, Dvec, delta, MROWS, H_DIM, H_DIM);
    // 5) Bm = a@WB + bB
    bm_k<<<(MROWS * DST) / 256, blk, 0, stream>>>(a_ws, WB, bB, Bm);
    // 6) output = (a*g)@Wf + bf  [4096 x 768, K=1536; fused a*g in staging]
    gemm_mx<0, true><<<dim3(DIM / 128, MROWS / 128), blk, 0, stream>>>(
        a_ws, g, Wfh, Wfl, bf, nullptr, out_y, MROWS, DIM, H_DIM);
    // 7-9) chunked selective scan -> hid
    scan_a<<<(B_SZ * CCH * HS) / 256, blk, 0, stream>>>(delta, a_ws, Bm, A, hend, Pprod);
    scan_b<<<(B_SZ * HS) / 256, blk, 0, stream>>>(hend, Pprod, Hinit);
    scan_c<<<(B_SZ * CCH * HS) / 256, blk, 0, stream>>>(delta, a_ws, Bm, A, Hinit, out_hid);
}